// Round 3
// baseline (1609.814 us; speedup 1.0000x reference)
//
#include <hip/hip_runtime.h>
#include <hip/hip_bf16.h>

// Problem constants
#define NN 50000
#define EE 800000
#define GG 1024
#define DD 300
#define DP 320        // padded feature dim (multiple of 32 for MFMA K)
#define LL 5
#define FEAT 256

typedef __bf16 bf16x8 __attribute__((ext_vector_type(8)));
typedef float  f32x4  __attribute__((ext_vector_type(4)));

// ---------------------------------------------------------------------------
// embed: AH[v][d] = x_emb1[x[v,0]][d] + x_emb2[x[v,1]][d]  (f32 in, bf16 out, pad 0)
__global__ void embed_kernel(const int* __restrict__ x,
                             const float* __restrict__ emb1,
                             const float* __restrict__ emb2,
                             __hip_bfloat16* __restrict__ A) {
    int idx = blockIdx.x * 256 + threadIdx.x;        // < NN*DP
    int v = idx / DP, d = idx % DP;
    float val = 0.f;
    if (d < DD) {
        int i0 = x[v * 2 + 0], i1 = x[v * 2 + 1];
        val = emb1[i0 * DD + d] + emb2[i1 * DD + d];
    }
    A[idx] = __float2bfloat16(val);
}

// ---------------------------------------------------------------------------
// histogram of destination (col) node degrees
__global__ void hist_kernel(const int* __restrict__ ei, int* __restrict__ deg) {
    int e = blockIdx.x * 256 + threadIdx.x;
    atomicAdd(&deg[ei[EE + e]], 1);
}

// 2-level exclusive scan
__global__ void scan1_kernel(const int* __restrict__ deg, int* __restrict__ ptr,
                             int* __restrict__ bsum) {
    __shared__ int buf[256];
    int tid = threadIdx.x;
    int i = blockIdx.x * 256 + tid;
    int v = (i < NN) ? deg[i] : 0;
    buf[tid] = v; __syncthreads();
    for (int off = 1; off < 256; off <<= 1) {
        int t = (tid >= off) ? buf[tid - off] : 0;
        __syncthreads();
        buf[tid] += t;
        __syncthreads();
    }
    if (i < NN) ptr[i + 1] = buf[tid];     // inclusive within block
    if (tid == 255) bsum[blockIdx.x] = buf[255];
}

__global__ void scan2_kernel(int* __restrict__ bsum) {   // 196 block sums -> exclusive
    __shared__ int buf[256];
    int tid = threadIdx.x;
    int v = (tid < 196) ? bsum[tid] : 0;
    buf[tid] = v; __syncthreads();
    for (int off = 1; off < 256; off <<= 1) {
        int t = (tid >= off) ? buf[tid - off] : 0;
        __syncthreads();
        buf[tid] += t;
        __syncthreads();
    }
    if (tid < 196) bsum[tid] = buf[tid] - v;  // exclusive
}

__global__ void scan3_kernel(int* __restrict__ ptr, const int* __restrict__ bsum) {
    int i = blockIdx.x * 256 + threadIdx.x;
    if (i < NN) ptr[i + 1] += bsum[blockIdx.x];
    if (i == 0) ptr[0] = 0;
}

// ---------------------------------------------------------------------------
// scatter edges into CSC src list; accumulate per-node edge-scalar sums for all layers.
// (self_e and b[l] are per-dim constants -> cancelled exactly by BatchNorm; dropped.)
__global__ void scatter_kernel(const int* __restrict__ ei, const int* __restrict__ ea,
                               const int* __restrict__ ptr, int* __restrict__ cur,
                               int* __restrict__ srcout,
                               const float* __restrict__ e1,
                               const float* __restrict__ e2,
                               float* __restrict__ S) {
    int e = blockIdx.x * 256 + threadIdx.x;
    int r = ei[e], c = ei[EE + e];
    int a0 = ea[e * 2 + 0], a1 = ea[e * 2 + 1];
    int pos = ptr[c] + atomicAdd(&cur[c], 1);
    srcout[pos] = r;
#pragma unroll
    for (int l = 0; l < LL; ++l) {
        float v = e1[l * 5 + a0] + e2[l * 3 + a1];
        atomicAdd(&S[l * NN + c], v);
    }
}

// ---------------------------------------------------------------------------
// repack W[l] (k,n row-major, 300x300 f32) -> WT[l] (n,k row-major, 320x320 bf16, zero pad)
__global__ void repack_kernel(const float* __restrict__ W,
                              __hip_bfloat16* __restrict__ WT) {
    int idx = blockIdx.x * 256 + threadIdx.x;       // < LL*DP*DP
    int l = idx / (DP * DP);
    int rem = idx - l * DP * DP;
    int n = rem / DP, k = rem % DP;
    float v = 0.f;
    if (n < DD && k < DD) v = W[l * DD * DD + k * DD + n];
    WT[idx] = __float2bfloat16(v);
}

// ---------------------------------------------------------------------------
// GEMM: C[M x 320] = A[M x 320] @ B[320 x 320], B given transposed (BT[n][k]).
// 128x160 tile, BK=32, 4 waves, each wave 64x80 via 4x5 mfma_f32_16x16x32_bf16.
__global__ __launch_bounds__(256) void gemm_kernel(
        const __hip_bfloat16* __restrict__ A, const __hip_bfloat16* __restrict__ BT,
        __hip_bfloat16* __restrict__ C, int M) {
    __shared__ __align__(16) __hip_bfloat16 As[128 * 40];   // row stride 40 (pad 8)
    __shared__ __align__(16) __hip_bfloat16 Bs[160 * 40];
    int tid = threadIdx.x;
    int m0 = blockIdx.x * 128, n0 = blockIdx.y * 160;
    int wave = tid >> 6, lane = tid & 63;
    int wm = (wave >> 1) * 64, wn = (wave & 1) * 80;
    int fm = lane & 15, fk = (lane >> 4) * 8;

    f32x4 acc[4][5];
#pragma unroll
    for (int i = 0; i < 4; ++i)
#pragma unroll
        for (int j = 0; j < 5; ++j) acc[i][j] = (f32x4){0.f, 0.f, 0.f, 0.f};

    for (int k0 = 0; k0 < DP; k0 += 32) {
        __syncthreads();
#pragma unroll
        for (int u = tid; u < 512; u += 256) {
            int r = u >> 2, p = u & 3;
            int gr = m0 + r;
            int4 val = make_int4(0, 0, 0, 0);
            if (gr < M) val = *reinterpret_cast<const int4*>(A + (size_t)gr * DP + k0 + p * 8);
            *reinterpret_cast<int4*>(As + r * 40 + p * 8) = val;
        }
        for (int u = tid; u < 640; u += 256) {
            int r = u >> 2, p = u & 3;
            *reinterpret_cast<int4*>(Bs + r * 40 + p * 8) =
                *reinterpret_cast<const int4*>(BT + (size_t)(n0 + r) * DP + k0 + p * 8);
        }
        __syncthreads();
        bf16x8 af[4], bfr[5];
#pragma unroll
        for (int mt = 0; mt < 4; ++mt)
            af[mt] = *reinterpret_cast<const bf16x8*>(As + (wm + mt * 16 + fm) * 40 + fk);
#pragma unroll
        for (int nt = 0; nt < 5; ++nt)
            bfr[nt] = *reinterpret_cast<const bf16x8*>(Bs + (wn + nt * 16 + fm) * 40 + fk);
#pragma unroll
        for (int mt = 0; mt < 4; ++mt)
#pragma unroll
            for (int nt = 0; nt < 5; ++nt)
                acc[mt][nt] = __builtin_amdgcn_mfma_f32_16x16x32_bf16(
                    af[mt], bfr[nt], acc[mt][nt], 0, 0, 0);
    }
    // epilogue: C/D layout col=lane&15, row=(lane>>4)*4+reg  [m89-verified]
    int cc = lane & 15, cr = (lane >> 4) * 4;
#pragma unroll
    for (int mt = 0; mt < 4; ++mt)
#pragma unroll
        for (int nt = 0; nt < 5; ++nt)
#pragma unroll
            for (int r = 0; r < 4; ++r) {
                int row = m0 + wm + mt * 16 + cr + r;
                if (row < M)
                    C[(size_t)row * DP + n0 + wn + nt * 16 + cc] =
                        __float2bfloat16(acc[mt][nt][r]);
            }
}

// ---------------------------------------------------------------------------
// aggregation: h_pre[v][d<300] = sum_{in-edges} hw[src][d] + hw[v][d] + s_l[v]
// writes bf16 h_pre back into AH (the gemm-input buffer, dead at this point).
// dims 300..319 written as 0 so AH stays a valid GEMM A matrix.
__global__ void agg_kernel(const __hip_bfloat16* __restrict__ HW,
                           const int* __restrict__ ptr, const int* __restrict__ src,
                           const float* __restrict__ Sl, __hip_bfloat16* __restrict__ AH) {
    int v = blockIdx.x * 4 + (threadIdx.x >> 6);
    int lane = threadIdx.x & 63;
    float a0 = 0.f, a1 = 0.f, a2 = 0.f, a3 = 0.f, a4 = 0.f;
    int beg = ptr[v], end = ptr[v + 1];
    for (int i = beg; i <= end; ++i) {          // i==end -> the self (hw[v]) term
        int s = (i < end) ? src[i] : v;
        const __hip_bfloat162* p = reinterpret_cast<const __hip_bfloat162*>(HW + (size_t)s * DP);
        __hip_bfloat162 x0 = p[lane];           // dims 2l,2l+1
        __hip_bfloat162 x1 = p[64 + lane];      // dims 128+2l
        float xs = __bfloat162float(HW[(size_t)s * DP + 256 + lane]);
        a0 += __bfloat162float(x0.x); a1 += __bfloat162float(x0.y);
        a2 += __bfloat162float(x1.x); a3 += __bfloat162float(x1.y);
        a4 += xs;
    }
    float sv = Sl[v];
    __hip_bfloat16* out = AH + (size_t)v * DP;
    __hip_bfloat162 o0, o1;
    o0.x = __float2bfloat16(a0 + sv); o0.y = __float2bfloat16(a1 + sv);
    o1.x = __float2bfloat16(a2 + sv); o1.y = __float2bfloat16(a3 + sv);
    *reinterpret_cast<__hip_bfloat162*>(out + 2 * lane) = o0;
    *reinterpret_cast<__hip_bfloat162*>(out + 128 + 2 * lane) = o1;
    out[256 + lane] = __float2bfloat16(lane < 44 ? a4 + sv : 0.f);  // 300..319 -> 0
}

// ---------------------------------------------------------------------------
// BN stats over bf16 h_pre (stride DP): sums[d], sums[DP+d]
__global__ void stats_kernel(const __hip_bfloat16* __restrict__ AH, float* __restrict__ sums) {
    int c = blockIdx.x;                 // dim chunk 0..4
    int tid = threadIdx.x;
    int dl = tid & 63, rl = tid >> 6;
    int d = c * 64 + dl;
    float s = 0.f, q = 0.f;
    if (d < DD) {
        for (int v = blockIdx.y * 4 + rl; v < NN; v += 256) {
            float x = __bfloat162float(AH[(size_t)v * DP + d]);
            s += x; q = fmaf(x, x, q);
        }
    }
    __shared__ float ls[256], lq[256];
    ls[tid] = s; lq[tid] = q;
    __syncthreads();
    if (tid < 64) {
        int dd = c * 64 + tid;
        if (dd < DD) {
            float ts = ls[tid] + ls[tid + 64] + ls[tid + 128] + ls[tid + 192];
            float tq = lq[tid] + lq[tid + 64] + lq[tid + 128] + lq[tid + 192];
            atomicAdd(&sums[dd], ts);
            atomicAdd(&sums[DP + dd], tq);
        }
    }
}

__global__ void finalize_kernel(const float* __restrict__ sums,
                                const float* __restrict__ gamma_l,
                                const float* __restrict__ beta_l,
                                float* __restrict__ scale, float* __restrict__ shift) {
    int d = threadIdx.x;                 // block of 320
    if (d < DD) {
        const float invN = 1.0f / (float)NN;
        float mean = sums[d] * invN;
        float var = sums[DP + d] * invN - mean * mean;
        var = fmaxf(var, 0.f);                      // guard fp32 cancellation
        float rs = rsqrtf(var + 1e-5f);
        float sc = rs * gamma_l[d];
        scale[d] = sc;
        shift[d] = beta_l[d] - mean * sc;
    }
}

// apply BN (+relu) IN PLACE on AH (element-wise, race-free); keeps pad dims 0
__global__ void apply_kernel(__hip_bfloat16* __restrict__ AH, const float* __restrict__ scale,
                             const float* __restrict__ shift, int relu) {
    int idx = blockIdx.x * 256 + threadIdx.x;    // < NN*DP
    int d = idx % DP;
    float val = 0.f;
    if (d < DD) {
        val = fmaf(__bfloat162float(AH[idx]), scale[d], shift[d]);
        if (relu) val = fmaxf(val, 0.f);
    }
    AH[idx] = __float2bfloat16(val);
}

// ---------------------------------------------------------------------------
__device__ __forceinline__ int lower_bound_dev(const int* b, int n, int key) {
    int lo = 0, hi = n;
    while (lo < hi) { int mid = (lo + hi) >> 1; if (b[mid] < key) lo = mid + 1; else hi = mid; }
    return lo;
}

// mean pool per graph: one wave per graph (batch sorted); f32 output
__global__ void pool_kernel(const __hip_bfloat16* __restrict__ A, const int* __restrict__ batch,
                            float* __restrict__ HG) {
    int g = blockIdx.x * 4 + (threadIdx.x >> 6);
    int lane = threadIdx.x & 63;
    int lo = lower_bound_dev(batch, NN, g);
    int hi = lower_bound_dev(batch, NN, g + 1);
    float a0 = 0.f, a1 = 0.f, a2 = 0.f, a3 = 0.f, a4 = 0.f;
    for (int v = lo; v < hi; ++v) {
        const __hip_bfloat162* p = reinterpret_cast<const __hip_bfloat162*>(A + (size_t)v * DP);
        __hip_bfloat162 x0 = p[lane];
        __hip_bfloat162 x1 = p[64 + lane];
        float xs = __bfloat162float(A[(size_t)v * DP + 256 + lane]);
        a0 += __bfloat162float(x0.x); a1 += __bfloat162float(x0.y);
        a2 += __bfloat162float(x1.x); a3 += __bfloat162float(x1.y);
        a4 += xs;
    }
    int cnt = hi - lo;
    float inv = 1.0f / (float)(cnt > 0 ? cnt : 1);
    float* out = HG + (size_t)g * DP;
    *reinterpret_cast<float2*>(out + 2 * lane)       = make_float2(a0 * inv, a1 * inv);
    *reinterpret_cast<float2*>(out + 128 + 2 * lane) = make_float2(a2 * inv, a3 * inv);
    out[256 + lane] = a4 * inv;   // lanes>=44 sum zero pad dims -> 0
}

// h_feat = hg @ feat_w + feat_b   (one block per graph), f32 out
__global__ void feat_kernel(const float* __restrict__ HG,
                            const float* __restrict__ fw,
                            const float* __restrict__ fb,
                            float* __restrict__ HFEAT, float* __restrict__ out0) {
    __shared__ float hgs[DD];
    int g = blockIdx.x, tid = threadIdx.x;
    for (int i = tid; i < DD; i += 256) hgs[i] = HG[(size_t)g * DP + i];
    __syncthreads();
    float acc = fb[tid];
#pragma unroll 4
    for (int k = 0; k < DD; ++k)
        acc = fmaf(hgs[k], fw[k * FEAT + tid], acc);
    HFEAT[g * FEAT + tid] = acc;
    out0[g * FEAT + tid] = acc;
}

// out = relu(h_feat @ w1 + b1) @ w2 + b2   (one block per graph), f32 out
__global__ void mlp_kernel(const float* __restrict__ HFEAT,
                           const float* __restrict__ w1, const float* __restrict__ b1,
                           const float* __restrict__ w2, const float* __restrict__ b2,
                           float* __restrict__ out1) {
    __shared__ float hf[FEAT], t[FEAT];
    int g = blockIdx.x, tid = threadIdx.x;
    hf[tid] = HFEAT[g * FEAT + tid];
    __syncthreads();
    float acc = b1[tid];
#pragma unroll 4
    for (int k = 0; k < FEAT; ++k)
        acc = fmaf(hf[k], w1[k * FEAT + tid], acc);
    t[tid] = fmaxf(acc, 0.f);
    __syncthreads();
    if (tid < FEAT / 2) {
        float acc2 = b2[tid];
#pragma unroll 4
        for (int k = 0; k < FEAT; ++k)
            acc2 = fmaf(t[k], w2[k * (FEAT / 2) + tid], acc2);
        out1[g * (FEAT / 2) + tid] = acc2;
    }
}

// ---------------------------------------------------------------------------
extern "C" void kernel_launch(void* const* d_in, const int* in_sizes, int n_in,
                              void* d_out, int out_size, void* d_ws, size_t ws_size,
                              hipStream_t stream) {
    const int* x     = (const int*)d_in[0];
    const int* ei    = (const int*)d_in[1];
    const int* ea    = (const int*)d_in[2];
    const int* batch = (const int*)d_in[3];
    const float* emb1  = (const float*)d_in[4];
    const float* emb2  = (const float*)d_in[5];
    const float* W     = (const float*)d_in[6];
    // d_in[7] = b[l]: per-dim constant, cancelled by BatchNorm -> unused
    const float* e1    = (const float*)d_in[8];
    const float* e2    = (const float*)d_in[9];
    const float* gamma = (const float*)d_in[10];
    const float* beta  = (const float*)d_in[11];
    const float* fw    = (const float*)d_in[12];
    const float* fb    = (const float*)d_in[13];
    const float* w1    = (const float*)d_in[14];
    const float* b1    = (const float*)d_in[15];
    const float* w2    = (const float*)d_in[16];
    const float* b2    = (const float*)d_in[17];

    // workspace carve (~70 MB total; small control buffers FIRST)
    char* base = (char*)d_ws;
    size_t off = 0;
    auto carve = [&](size_t bytes) -> void* {
        void* p = base + off;
        off = (off + bytes + 255) & ~(size_t)255;
        return p;
    };
    int*            PTR   = (int*)carve((size_t)(NN + 1) * 4);
    int*            CUR   = (int*)carve((size_t)NN * 4);
    int*            SRC   = (int*)carve((size_t)EE * 4);
    float*          S     = (float*)carve((size_t)LL * NN * 4);
    int*            BSUM  = (int*)carve(256 * 4);
    float*          SUMS  = (float*)carve(2 * DP * 4);
    float*          SCALE = (float*)carve(DP * 4);
    float*          SHIFT = (float*)carve(DP * 4);
    float*          HG    = (float*)carve((size_t)GG * DP * 4);
    float*          HFEAT = (float*)carve((size_t)GG * FEAT * 4);
    __hip_bfloat16* WT    = (__hip_bfloat16*)carve((size_t)LL * DP * DP * 2);
    __hip_bfloat16* AH    = (__hip_bfloat16*)carve((size_t)NN * DP * 2);  // A / h_pre ping
    __hip_bfloat16* HWb   = (__hip_bfloat16*)carve((size_t)NN * DP * 2);  // gemm out pong

    float* out0 = (float*)d_out;                 // h_feat [G,256] f32
    float* out1 = (float*)d_out + GG * FEAT;     // out    [G,128] f32

    // ---- preprocess (ws is re-poisoned before every call) ----
    hipMemsetAsync(CUR, 0, (size_t)NN * 4, stream);
    hipMemsetAsync(S, 0, (size_t)LL * NN * 4, stream);
    embed_kernel<<<(NN * DP) / 256, 256, 0, stream>>>(x, emb1, emb2, AH);
    hist_kernel<<<EE / 256, 256, 0, stream>>>(ei, CUR);
    scan1_kernel<<<196, 256, 0, stream>>>(CUR, PTR, BSUM);
    scan2_kernel<<<1, 256, 0, stream>>>(BSUM);
    scan3_kernel<<<196, 256, 0, stream>>>(PTR, BSUM);
    hipMemsetAsync(CUR, 0, (size_t)NN * 4, stream);
    scatter_kernel<<<EE / 256, 256, 0, stream>>>(ei, ea, PTR, CUR, SRC, e1, e2, S);
    repack_kernel<<<(LL * DP * DP) / 256, 256, 0, stream>>>(W, WT);

    // ---- layers ----
    for (int l = 0; l < LL; ++l) {
        gemm_kernel<<<dim3(391, 2), 256, 0, stream>>>(AH, WT + (size_t)l * DP * DP, HWb, NN);
        agg_kernel<<<NN / 4, 256, 0, stream>>>(HWb, PTR, SRC, S + (size_t)l * NN, AH);
        hipMemsetAsync(SUMS, 0, 2 * DP * 4, stream);
        stats_kernel<<<dim3(5, 64), 256, 0, stream>>>(AH, SUMS);
        finalize_kernel<<<1, 320, 0, stream>>>(SUMS, gamma + l * DD, beta + l * DD, SCALE, SHIFT);
        apply_kernel<<<(NN * DP) / 256, 256, 0, stream>>>(AH, SCALE, SHIFT, l < LL - 1 ? 1 : 0);
    }

    // ---- head ----
    pool_kernel<<<GG / 4, 256, 0, stream>>>(AH, batch, HG);
    feat_kernel<<<GG, 256, 0, stream>>>(HG, fw, fb, HFEAT, out0);
    mlp_kernel<<<GG, 256, 0, stream>>>(HFEAT, w1, b1, w2, b2, out1);
}

// Round 4
// 1422.221 us; speedup vs baseline: 1.1319x; 1.1319x over previous
//
#include <hip/hip_runtime.h>
#include <hip/hip_bf16.h>

// Problem constants
#define NN 50000
#define EE 800000
#define GG 1024
#define DD 300
#define DP 320        // padded feature dim (multiple of 32 for MFMA K)
#define LL 5
#define FEAT 256

typedef __bf16 bf16x8 __attribute__((ext_vector_type(8)));
typedef float  f32x4  __attribute__((ext_vector_type(4)));

// ---------------------------------------------------------------------------
// embed: AH[v][d] = x_emb1[x[v,0]][d] + x_emb2[x[v,1]][d]  (f32 in, bf16 out, pad 0)
__global__ void embed_kernel(const int* __restrict__ x,
                             const float* __restrict__ emb1,
                             const float* __restrict__ emb2,
                             __hip_bfloat16* __restrict__ A) {
    int idx = blockIdx.x * 256 + threadIdx.x;        // < NN*DP
    int v = idx / DP, d = idx % DP;
    float val = 0.f;
    if (d < DD) {
        int i0 = x[v * 2 + 0], i1 = x[v * 2 + 1];
        val = emb1[i0 * DD + d] + emb2[i1 * DD + d];
    }
    A[idx] = __float2bfloat16(val);
}

// ---------------------------------------------------------------------------
// histogram of destination (col) node degrees
__global__ void hist_kernel(const int* __restrict__ ei, int* __restrict__ deg) {
    int e = blockIdx.x * 256 + threadIdx.x;
    atomicAdd(&deg[ei[EE + e]], 1);
}

// 2-level exclusive scan
__global__ void scan1_kernel(const int* __restrict__ deg, int* __restrict__ ptr,
                             int* __restrict__ bsum) {
    __shared__ int buf[256];
    int tid = threadIdx.x;
    int i = blockIdx.x * 256 + tid;
    int v = (i < NN) ? deg[i] : 0;
    buf[tid] = v; __syncthreads();
    for (int off = 1; off < 256; off <<= 1) {
        int t = (tid >= off) ? buf[tid - off] : 0;
        __syncthreads();
        buf[tid] += t;
        __syncthreads();
    }
    if (i < NN) ptr[i + 1] = buf[tid];     // inclusive within block
    if (tid == 255) bsum[blockIdx.x] = buf[255];
}

__global__ void scan2_kernel(int* __restrict__ bsum) {   // 196 block sums -> exclusive
    __shared__ int buf[256];
    int tid = threadIdx.x;
    int v = (tid < 196) ? bsum[tid] : 0;
    buf[tid] = v; __syncthreads();
    for (int off = 1; off < 256; off <<= 1) {
        int t = (tid >= off) ? buf[tid - off] : 0;
        __syncthreads();
        buf[tid] += t;
        __syncthreads();
    }
    if (tid < 196) bsum[tid] = buf[tid] - v;  // exclusive
}

__global__ void scan3_kernel(int* __restrict__ ptr, const int* __restrict__ bsum) {
    int i = blockIdx.x * 256 + threadIdx.x;
    if (i < NN) ptr[i + 1] += bsum[blockIdx.x];
    if (i == 0) ptr[0] = 0;
}

// ---------------------------------------------------------------------------
// scatter edges into CSC src list; PACK edge attrs into spare bits of the src id
// (r < 65536 fits in 16 bits; a0,a1 in 2 bits each). The per-node edge-scalar
// sums are reconstructed in agg_kernel from attr counts -> no float atomics here.
// (self_e and b[l] are per-dim constants -> cancelled exactly by BatchNorm; dropped.)
__global__ void scatter_kernel(const int* __restrict__ ei, const int* __restrict__ ea,
                               const int* __restrict__ ptr, int* __restrict__ cur,
                               int* __restrict__ srcout) {
    int e = blockIdx.x * 256 + threadIdx.x;
    int r = ei[e], c = ei[EE + e];
    int a0 = ea[e * 2 + 0], a1 = ea[e * 2 + 1];
    int pos = ptr[c] + atomicAdd(&cur[c], 1);
    srcout[pos] = r | (a0 << 16) | (a1 << 18);
}

// ---------------------------------------------------------------------------
// repack W[l] (k,n row-major, 300x300 f32) -> WT[l] (n,k row-major, 320x320 bf16, zero pad)
__global__ void repack_kernel(const float* __restrict__ W,
                              __hip_bfloat16* __restrict__ WT) {
    int idx = blockIdx.x * 256 + threadIdx.x;       // < LL*DP*DP
    int l = idx / (DP * DP);
    int rem = idx - l * DP * DP;
    int n = rem / DP, k = rem % DP;
    float v = 0.f;
    if (n < DD && k < DD) v = W[l * DD * DD + k * DD + n];
    WT[idx] = __float2bfloat16(v);
}

// ---------------------------------------------------------------------------
// GEMM: C[M x 320] = A[M x 320] @ B[320 x 320], B given transposed (BT[n][k]).
// 128x160 tile, BK=32, 4 waves, each wave 64x80 via 4x5 mfma_f32_16x16x32_bf16.
__global__ __launch_bounds__(256) void gemm_kernel(
        const __hip_bfloat16* __restrict__ A, const __hip_bfloat16* __restrict__ BT,
        __hip_bfloat16* __restrict__ C, int M) {
    __shared__ __align__(16) __hip_bfloat16 As[128 * 40];   // row stride 40 (pad 8)
    __shared__ __align__(16) __hip_bfloat16 Bs[160 * 40];
    int tid = threadIdx.x;
    int m0 = blockIdx.x * 128, n0 = blockIdx.y * 160;
    int wave = tid >> 6, lane = tid & 63;
    int wm = (wave >> 1) * 64, wn = (wave & 1) * 80;
    int fm = lane & 15, fk = (lane >> 4) * 8;

    f32x4 acc[4][5];
#pragma unroll
    for (int i = 0; i < 4; ++i)
#pragma unroll
        for (int j = 0; j < 5; ++j) acc[i][j] = (f32x4){0.f, 0.f, 0.f, 0.f};

    for (int k0 = 0; k0 < DP; k0 += 32) {
        __syncthreads();
#pragma unroll
        for (int u = tid; u < 512; u += 256) {
            int r = u >> 2, p = u & 3;
            int gr = m0 + r;
            int4 val = make_int4(0, 0, 0, 0);
            if (gr < M) val = *reinterpret_cast<const int4*>(A + (size_t)gr * DP + k0 + p * 8);
            *reinterpret_cast<int4*>(As + r * 40 + p * 8) = val;
        }
        for (int u = tid; u < 640; u += 256) {
            int r = u >> 2, p = u & 3;
            *reinterpret_cast<int4*>(Bs + r * 40 + p * 8) =
                *reinterpret_cast<const int4*>(BT + (size_t)(n0 + r) * DP + k0 + p * 8);
        }
        __syncthreads();
        bf16x8 af[4], bfr[5];
#pragma unroll
        for (int mt = 0; mt < 4; ++mt)
            af[mt] = *reinterpret_cast<const bf16x8*>(As + (wm + mt * 16 + fm) * 40 + fk);
#pragma unroll
        for (int nt = 0; nt < 5; ++nt)
            bfr[nt] = *reinterpret_cast<const bf16x8*>(Bs + (wn + nt * 16 + fm) * 40 + fk);
#pragma unroll
        for (int mt = 0; mt < 4; ++mt)
#pragma unroll
            for (int nt = 0; nt < 5; ++nt)
                acc[mt][nt] = __builtin_amdgcn_mfma_f32_16x16x32_bf16(
                    af[mt], bfr[nt], acc[mt][nt], 0, 0, 0);
    }
    // epilogue: C/D layout col=lane&15, row=(lane>>4)*4+reg  [m89-verified]
    int cc = lane & 15, cr = (lane >> 4) * 4;
#pragma unroll
    for (int mt = 0; mt < 4; ++mt)
#pragma unroll
        for (int nt = 0; nt < 5; ++nt)
#pragma unroll
            for (int r = 0; r < 4; ++r) {
                int row = m0 + wm + mt * 16 + cr + r;
                if (row < M)
                    C[(size_t)row * DP + n0 + wn + nt * 16 + cc] =
                        __float2bfloat16(acc[mt][nt][r]);
            }
}

// ---------------------------------------------------------------------------
// aggregation: h_pre[v][d<300] = sum_{in-edges} hw[src][d] + hw[v][d] + s_l[v]
// s_l[v] reconstructed from packed per-edge attrs: s_l[v] = sum_j c0[j]*e1l[j] + c1[j]*e2l[j].
// writes bf16 h_pre back into AH (the gemm-input buffer, dead at this point).
// dims 300..319 written as 0 so AH stays a valid GEMM A matrix.
__global__ void agg_kernel(const __hip_bfloat16* __restrict__ HW,
                           const int* __restrict__ ptr, const int* __restrict__ src,
                           const float* __restrict__ e1l, const float* __restrict__ e2l,
                           __hip_bfloat16* __restrict__ AH) {
    int v = blockIdx.x * 4 + (threadIdx.x >> 6);
    int lane = threadIdx.x & 63;
    float a0 = 0.f, a1 = 0.f, a2 = 0.f, a3 = 0.f, a4 = 0.f;
    float c00 = 0.f, c01 = 0.f, c02 = 0.f, c10 = 0.f, c11 = 0.f, c12 = 0.f;
    int beg = ptr[v], end = ptr[v + 1];
    for (int i = beg; i <= end; ++i) {          // i==end -> the self (hw[v]) term
        int s = v;
        if (i < end) {
            int packed = src[i];
            s = packed & 0xFFFF;
            int e0 = (packed >> 16) & 3, e1v = (packed >> 18) & 3;
            c00 += (e0 == 0); c01 += (e0 == 1); c02 += (e0 == 2);
            c10 += (e1v == 0); c11 += (e1v == 1); c12 += (e1v == 2);
        }
        const __hip_bfloat162* p = reinterpret_cast<const __hip_bfloat162*>(HW + (size_t)s * DP);
        __hip_bfloat162 x0 = p[lane];           // dims 2l,2l+1
        __hip_bfloat162 x1 = p[64 + lane];      // dims 128+2l
        float xs = __bfloat162float(HW[(size_t)s * DP + 256 + lane]);
        a0 += __bfloat162float(x0.x); a1 += __bfloat162float(x0.y);
        a2 += __bfloat162float(x1.x); a3 += __bfloat162float(x1.y);
        a4 += xs;
    }
    float sv = c00 * e1l[0] + c01 * e1l[1] + c02 * e1l[2]
             + c10 * e2l[0] + c11 * e2l[1] + c12 * e2l[2];
    __hip_bfloat16* out = AH + (size_t)v * DP;
    __hip_bfloat162 o0, o1;
    o0.x = __float2bfloat16(a0 + sv); o0.y = __float2bfloat16(a1 + sv);
    o1.x = __float2bfloat16(a2 + sv); o1.y = __float2bfloat16(a3 + sv);
    *reinterpret_cast<__hip_bfloat162*>(out + 2 * lane) = o0;
    *reinterpret_cast<__hip_bfloat162*>(out + 128 + 2 * lane) = o1;
    out[256 + lane] = __float2bfloat16(lane < 44 ? a4 + sv : 0.f);  // 300..319 -> 0
}

// ---------------------------------------------------------------------------
// BN stats over bf16 h_pre (stride DP): sums[d], sums[DP+d]
__global__ void stats_kernel(const __hip_bfloat16* __restrict__ AH, float* __restrict__ sums) {
    int c = blockIdx.x;                 // dim chunk 0..4
    int tid = threadIdx.x;
    int dl = tid & 63, rl = tid >> 6;
    int d = c * 64 + dl;
    float s = 0.f, q = 0.f;
    if (d < DD) {
        for (int v = blockIdx.y * 4 + rl; v < NN; v += 256) {
            float x = __bfloat162float(AH[(size_t)v * DP + d]);
            s += x; q = fmaf(x, x, q);
        }
    }
    __shared__ float ls[256], lq[256];
    ls[tid] = s; lq[tid] = q;
    __syncthreads();
    if (tid < 64) {
        int dd = c * 64 + tid;
        if (dd < DD) {
            float ts = ls[tid] + ls[tid + 64] + ls[tid + 128] + ls[tid + 192];
            float tq = lq[tid] + lq[tid + 64] + lq[tid + 128] + lq[tid + 192];
            atomicAdd(&sums[dd], ts);
            atomicAdd(&sums[DP + dd], tq);
        }
    }
}

__global__ void finalize_kernel(const float* __restrict__ sums,
                                const float* __restrict__ gamma_l,
                                const float* __restrict__ beta_l,
                                float* __restrict__ scale, float* __restrict__ shift) {
    int d = threadIdx.x;                 // block of 320
    if (d < DD) {
        const float invN = 1.0f / (float)NN;
        float mean = sums[d] * invN;
        float var = sums[DP + d] * invN - mean * mean;
        var = fmaxf(var, 0.f);                      // guard fp32 cancellation
        float rs = rsqrtf(var + 1e-5f);
        float sc = rs * gamma_l[d];
        scale[d] = sc;
        shift[d] = beta_l[d] - mean * sc;
    }
}

// apply BN (+relu) IN PLACE on AH (element-wise, race-free); keeps pad dims 0
__global__ void apply_kernel(__hip_bfloat16* __restrict__ AH, const float* __restrict__ scale,
                             const float* __restrict__ shift, int relu) {
    int idx = blockIdx.x * 256 + threadIdx.x;    // < NN*DP
    int d = idx % DP;
    float val = 0.f;
    if (d < DD) {
        val = fmaf(__bfloat162float(AH[idx]), scale[d], shift[d]);
        if (relu) val = fmaxf(val, 0.f);
    }
    AH[idx] = __float2bfloat16(val);
}

// ---------------------------------------------------------------------------
__device__ __forceinline__ int lower_bound_dev(const int* b, int n, int key) {
    int lo = 0, hi = n;
    while (lo < hi) { int mid = (lo + hi) >> 1; if (b[mid] < key) lo = mid + 1; else hi = mid; }
    return lo;
}

// mean pool per graph: one wave per graph (batch sorted); f32 output
__global__ void pool_kernel(const __hip_bfloat16* __restrict__ A, const int* __restrict__ batch,
                            float* __restrict__ HG) {
    int g = blockIdx.x * 4 + (threadIdx.x >> 6);
    int lane = threadIdx.x & 63;
    int lo = lower_bound_dev(batch, NN, g);
    int hi = lower_bound_dev(batch, NN, g + 1);
    float a0 = 0.f, a1 = 0.f, a2 = 0.f, a3 = 0.f, a4 = 0.f;
    for (int v = lo; v < hi; ++v) {
        const __hip_bfloat162* p = reinterpret_cast<const __hip_bfloat162*>(A + (size_t)v * DP);
        __hip_bfloat162 x0 = p[lane];
        __hip_bfloat162 x1 = p[64 + lane];
        float xs = __bfloat162float(A[(size_t)v * DP + 256 + lane]);
        a0 += __bfloat162float(x0.x); a1 += __bfloat162float(x0.y);
        a2 += __bfloat162float(x1.x); a3 += __bfloat162float(x1.y);
        a4 += xs;
    }
    int cnt = hi - lo;
    float inv = 1.0f / (float)(cnt > 0 ? cnt : 1);
    float* out = HG + (size_t)g * DP;
    *reinterpret_cast<float2*>(out + 2 * lane)       = make_float2(a0 * inv, a1 * inv);
    *reinterpret_cast<float2*>(out + 128 + 2 * lane) = make_float2(a2 * inv, a3 * inv);
    out[256 + lane] = a4 * inv;   // lanes>=44 sum zero pad dims -> 0
}

// h_feat = hg @ feat_w + feat_b   (one block per graph), f32 out
__global__ void feat_kernel(const float* __restrict__ HG,
                            const float* __restrict__ fw,
                            const float* __restrict__ fb,
                            float* __restrict__ HFEAT, float* __restrict__ out0) {
    __shared__ float hgs[DD];
    int g = blockIdx.x, tid = threadIdx.x;
    for (int i = tid; i < DD; i += 256) hgs[i] = HG[(size_t)g * DP + i];
    __syncthreads();
    float acc = fb[tid];
#pragma unroll 4
    for (int k = 0; k < DD; ++k)
        acc = fmaf(hgs[k], fw[k * FEAT + tid], acc);
    HFEAT[g * FEAT + tid] = acc;
    out0[g * FEAT + tid] = acc;
}

// out = relu(h_feat @ w1 + b1) @ w2 + b2   (one block per graph), f32 out
__global__ void mlp_kernel(const float* __restrict__ HFEAT,
                           const float* __restrict__ w1, const float* __restrict__ b1,
                           const float* __restrict__ w2, const float* __restrict__ b2,
                           float* __restrict__ out1) {
    __shared__ float hf[FEAT], t[FEAT];
    int g = blockIdx.x, tid = threadIdx.x;
    hf[tid] = HFEAT[g * FEAT + tid];
    __syncthreads();
    float acc = b1[tid];
#pragma unroll 4
    for (int k = 0; k < FEAT; ++k)
        acc = fmaf(hf[k], w1[k * FEAT + tid], acc);
    t[tid] = fmaxf(acc, 0.f);
    __syncthreads();
    if (tid < FEAT / 2) {
        float acc2 = b2[tid];
#pragma unroll 4
        for (int k = 0; k < FEAT; ++k)
            acc2 = fmaf(t[k], w2[k * (FEAT / 2) + tid], acc2);
        out1[g * (FEAT / 2) + tid] = acc2;
    }
}

// ---------------------------------------------------------------------------
extern "C" void kernel_launch(void* const* d_in, const int* in_sizes, int n_in,
                              void* d_out, int out_size, void* d_ws, size_t ws_size,
                              hipStream_t stream) {
    const int* x     = (const int*)d_in[0];
    const int* ei    = (const int*)d_in[1];
    const int* ea    = (const int*)d_in[2];
    const int* batch = (const int*)d_in[3];
    const float* emb1  = (const float*)d_in[4];
    const float* emb2  = (const float*)d_in[5];
    const float* W     = (const float*)d_in[6];
    // d_in[7] = b[l]: per-dim constant, cancelled by BatchNorm -> unused
    const float* e1    = (const float*)d_in[8];
    const float* e2    = (const float*)d_in[9];
    const float* gamma = (const float*)d_in[10];
    const float* beta  = (const float*)d_in[11];
    const float* fw    = (const float*)d_in[12];
    const float* fb    = (const float*)d_in[13];
    const float* w1    = (const float*)d_in[14];
    const float* b1    = (const float*)d_in[15];
    const float* w2    = (const float*)d_in[16];
    const float* b2    = (const float*)d_in[17];

    // workspace carve (~69 MB total; small control buffers FIRST)
    char* base = (char*)d_ws;
    size_t off = 0;
    auto carve = [&](size_t bytes) -> void* {
        void* p = base + off;
        off = (off + bytes + 255) & ~(size_t)255;
        return p;
    };
    int*            PTR   = (int*)carve((size_t)(NN + 1) * 4);
    int*            CUR   = (int*)carve((size_t)NN * 4);
    int*            SRC   = (int*)carve((size_t)EE * 4);
    int*            BSUM  = (int*)carve(256 * 4);
    float*          SUMS  = (float*)carve(2 * DP * 4);
    float*          SCALE = (float*)carve(DP * 4);
    float*          SHIFT = (float*)carve(DP * 4);
    float*          HG    = (float*)carve((size_t)GG * DP * 4);
    float*          HFEAT = (float*)carve((size_t)GG * FEAT * 4);
    __hip_bfloat16* WT    = (__hip_bfloat16*)carve((size_t)LL * DP * DP * 2);
    __hip_bfloat16* AH    = (__hip_bfloat16*)carve((size_t)NN * DP * 2);  // A / h_pre ping
    __hip_bfloat16* HWb   = (__hip_bfloat16*)carve((size_t)NN * DP * 2);  // gemm out pong

    float* out0 = (float*)d_out;                 // h_feat [G,256] f32
    float* out1 = (float*)d_out + GG * FEAT;     // out    [G,128] f32

    // ---- preprocess (ws is re-poisoned before every call) ----
    hipMemsetAsync(CUR, 0, (size_t)NN * 4, stream);
    embed_kernel<<<(NN * DP) / 256, 256, 0, stream>>>(x, emb1, emb2, AH);
    hist_kernel<<<EE / 256, 256, 0, stream>>>(ei, CUR);
    scan1_kernel<<<196, 256, 0, stream>>>(CUR, PTR, BSUM);
    scan2_kernel<<<1, 256, 0, stream>>>(BSUM);
    scan3_kernel<<<196, 256, 0, stream>>>(PTR, BSUM);
    hipMemsetAsync(CUR, 0, (size_t)NN * 4, stream);
    scatter_kernel<<<EE / 256, 256, 0, stream>>>(ei, ea, PTR, CUR, SRC);
    repack_kernel<<<(LL * DP * DP) / 256, 256, 0, stream>>>(W, WT);

    // ---- layers ----
    for (int l = 0; l < LL; ++l) {
        gemm_kernel<<<dim3(391, 2), 256, 0, stream>>>(AH, WT + (size_t)l * DP * DP, HWb, NN);
        agg_kernel<<<NN / 4, 256, 0, stream>>>(HWb, PTR, SRC, e1 + l * 5, e2 + l * 3, AH);
        hipMemsetAsync(SUMS, 0, 2 * DP * 4, stream);
        stats_kernel<<<dim3(5, 64), 256, 0, stream>>>(AH, SUMS);
        finalize_kernel<<<1, 320, 0, stream>>>(SUMS, gamma + l * DD, beta + l * DD, SCALE, SHIFT);
        apply_kernel<<<(NN * DP) / 256, 256, 0, stream>>>(AH, SCALE, SHIFT, l < LL - 1 ? 1 : 0);
    }

    // ---- head ----
    pool_kernel<<<GG / 4, 256, 0, stream>>>(AH, batch, HG);
    feat_kernel<<<GG, 256, 0, stream>>>(HG, fw, fb, HFEAT, out0);
    mlp_kernel<<<GG, 256, 0, stream>>>(HFEAT, w1, b1, w2, b2, out1);
}

// Round 5
// 1191.273 us; speedup vs baseline: 1.3513x; 1.1939x over previous
//
#include <hip/hip_runtime.h>
#include <hip/hip_bf16.h>

// Problem constants
#define NN 50000
#define EE 800000
#define GG 1024
#define DD 300
#define DP 320        // padded feature dim (multiple of 32 for MFMA K)
#define LL 5
#define FEAT 256

typedef __bf16 bf16x8 __attribute__((ext_vector_type(8)));
typedef float  f32x4  __attribute__((ext_vector_type(4)));

// ---------------------------------------------------------------------------
// embed: AH[v][d] = x_emb1[x[v,0]][d] + x_emb2[x[v,1]][d]  (f32 in, bf16 out, pad 0)
__global__ void embed_kernel(const int* __restrict__ x,
                             const float* __restrict__ emb1,
                             const float* __restrict__ emb2,
                             __hip_bfloat16* __restrict__ A) {
    int idx = blockIdx.x * 256 + threadIdx.x;        // < NN*DP
    int v = idx / DP, d = idx % DP;
    float val = 0.f;
    if (d < DD) {
        int i0 = x[v * 2 + 0], i1 = x[v * 2 + 1];
        val = emb1[i0 * DD + d] + emb2[i1 * DD + d];
    }
    A[idx] = __float2bfloat16(val);
}

// ---------------------------------------------------------------------------
// histogram of destination (col) node degrees
__global__ void hist_kernel(const int* __restrict__ ei, int* __restrict__ deg) {
    int e = blockIdx.x * 256 + threadIdx.x;
    atomicAdd(&deg[ei[EE + e]], 1);
}

// 2-level exclusive scan
__global__ void scan1_kernel(const int* __restrict__ deg, int* __restrict__ ptr,
                             int* __restrict__ bsum) {
    __shared__ int buf[256];
    int tid = threadIdx.x;
    int i = blockIdx.x * 256 + tid;
    int v = (i < NN) ? deg[i] : 0;
    buf[tid] = v; __syncthreads();
    for (int off = 1; off < 256; off <<= 1) {
        int t = (tid >= off) ? buf[tid - off] : 0;
        __syncthreads();
        buf[tid] += t;
        __syncthreads();
    }
    if (i < NN) ptr[i + 1] = buf[tid];     // inclusive within block
    if (tid == 255) bsum[blockIdx.x] = buf[255];
}

__global__ void scan2_kernel(int* __restrict__ bsum) {   // 196 block sums -> exclusive
    __shared__ int buf[256];
    int tid = threadIdx.x;
    int v = (tid < 196) ? bsum[tid] : 0;
    buf[tid] = v; __syncthreads();
    for (int off = 1; off < 256; off <<= 1) {
        int t = (tid >= off) ? buf[tid - off] : 0;
        __syncthreads();
        buf[tid] += t;
        __syncthreads();
    }
    if (tid < 196) bsum[tid] = buf[tid] - v;  // exclusive
}

__global__ void scan3_kernel(int* __restrict__ ptr, const int* __restrict__ bsum) {
    int i = blockIdx.x * 256 + threadIdx.x;
    if (i < NN) ptr[i + 1] += bsum[blockIdx.x];
    if (i == 0) ptr[0] = 0;
}

// ---------------------------------------------------------------------------
// scatter edges into CSC src list; PACK edge attrs into spare bits of the src id
// (r < 65536 fits in 16 bits; a0,a1 in 2 bits each).
// (self_e and b[l] are per-dim constants -> cancelled exactly by BatchNorm; dropped.)
__global__ void scatter_kernel(const int* __restrict__ ei, const int* __restrict__ ea,
                               const int* __restrict__ ptr, int* __restrict__ cur,
                               int* __restrict__ srcout) {
    int e = blockIdx.x * 256 + threadIdx.x;
    int r = ei[e], c = ei[EE + e];
    int a0 = ea[e * 2 + 0], a1 = ea[e * 2 + 1];
    int pos = ptr[c] + atomicAdd(&cur[c], 1);
    srcout[pos] = r | (a0 << 16) | (a1 << 18);
}

// ---------------------------------------------------------------------------
// per-node per-layer edge-scalar sums, no atomics: one thread per node walks
// its CSC in-edge list once; SV[l][v] = sum_edges e1[l,a0] + e2[l,a1]
__global__ void sv_kernel(const int* __restrict__ ptr, const int* __restrict__ src,
                          const float* __restrict__ e1, const float* __restrict__ e2,
                          float* __restrict__ SV) {
    int v = blockIdx.x * 256 + threadIdx.x;
    if (v >= NN) return;
    float c00 = 0.f, c01 = 0.f, c02 = 0.f, c10 = 0.f, c11 = 0.f, c12 = 0.f;
    int beg = ptr[v], end = ptr[v + 1];
    for (int i = beg; i < end; ++i) {
        int p = src[i];
        int e0 = (p >> 16) & 3, ev = (p >> 18) & 3;
        c00 += (e0 == 0); c01 += (e0 == 1); c02 += (e0 == 2);
        c10 += (ev == 0); c11 += (ev == 1); c12 += (ev == 2);
    }
#pragma unroll
    for (int l = 0; l < LL; ++l) {
        float s = c00 * e1[l * 5 + 0] + c01 * e1[l * 5 + 1] + c02 * e1[l * 5 + 2]
                + c10 * e2[l * 3 + 0] + c11 * e2[l * 3 + 1] + c12 * e2[l * 3 + 2];
        SV[l * NN + v] = s;
    }
}

// ---------------------------------------------------------------------------
// repack W[l] (k,n row-major, 300x300 f32) -> WT[l] (n,k row-major, 320x320 bf16, zero pad)
__global__ void repack_kernel(const float* __restrict__ W,
                              __hip_bfloat16* __restrict__ WT) {
    int idx = blockIdx.x * 256 + threadIdx.x;       // < LL*DP*DP
    int l = idx / (DP * DP);
    int rem = idx - l * DP * DP;
    int n = rem / DP, k = rem % DP;
    float v = 0.f;
    if (n < DD && k < DD) v = W[l * DD * DD + k * DD + n];
    WT[idx] = __float2bfloat16(v);
}

// ---------------------------------------------------------------------------
// GEMM: C[M x 320] = act(A) [M x 320] @ B [320 x 320], B transposed (BT[n][k]).
// fold!=0: act(x) = relu(x*scale[k]+shift[k]) applied during A-staging (BN of
// the previous layer fused; scale/shift are 0 on pad dims so padding stays 0).
// 128x160 tile, BK=32, 4 waves, each wave 64x80 via 4x5 mfma_f32_16x16x32_bf16.
__global__ __launch_bounds__(256) void gemm_kernel(
        const __hip_bfloat16* __restrict__ A, const __hip_bfloat16* __restrict__ BT,
        __hip_bfloat16* __restrict__ C, int M,
        const float* __restrict__ scale, const float* __restrict__ shift, int fold) {
    __shared__ __align__(16) __hip_bfloat16 As[128 * 40];   // row stride 40 (pad 8)
    __shared__ __align__(16) __hip_bfloat16 Bs[160 * 40];
    int tid = threadIdx.x;
    int m0 = blockIdx.x * 128, n0 = blockIdx.y * 160;
    int wave = tid >> 6, lane = tid & 63;
    int wm = (wave >> 1) * 64, wn = (wave & 1) * 80;
    int fm = lane & 15, fk = (lane >> 4) * 8;

    f32x4 acc[4][5];
#pragma unroll
    for (int i = 0; i < 4; ++i)
#pragma unroll
        for (int j = 0; j < 5; ++j) acc[i][j] = (f32x4){0.f, 0.f, 0.f, 0.f};

    for (int k0 = 0; k0 < DP; k0 += 32) {
        __syncthreads();
#pragma unroll
        for (int u = tid; u < 512; u += 256) {
            int r = u >> 2, p = u & 3;
            int gr = m0 + r;
            int4 val = make_int4(0, 0, 0, 0);
            if (gr < M) {
                val = *reinterpret_cast<const int4*>(A + (size_t)gr * DP + k0 + p * 8);
                if (fold) {
                    __hip_bfloat16* hh = reinterpret_cast<__hip_bfloat16*>(&val);
                    int kb = k0 + p * 8;
#pragma unroll
                    for (int j = 0; j < 8; ++j) {
                        float f = fmaf(__bfloat162float(hh[j]), scale[kb + j], shift[kb + j]);
                        hh[j] = __float2bfloat16(fmaxf(f, 0.f));
                    }
                }
            }
            *reinterpret_cast<int4*>(As + r * 40 + p * 8) = val;
        }
        for (int u = tid; u < 640; u += 256) {
            int r = u >> 2, p = u & 3;
            *reinterpret_cast<int4*>(Bs + r * 40 + p * 8) =
                *reinterpret_cast<const int4*>(BT + (size_t)(n0 + r) * DP + k0 + p * 8);
        }
        __syncthreads();
        bf16x8 af[4], bfr[5];
#pragma unroll
        for (int mt = 0; mt < 4; ++mt)
            af[mt] = *reinterpret_cast<const bf16x8*>(As + (wm + mt * 16 + fm) * 40 + fk);
#pragma unroll
        for (int nt = 0; nt < 5; ++nt)
            bfr[nt] = *reinterpret_cast<const bf16x8*>(Bs + (wn + nt * 16 + fm) * 40 + fk);
#pragma unroll
        for (int mt = 0; mt < 4; ++mt)
#pragma unroll
            for (int nt = 0; nt < 5; ++nt)
                acc[mt][nt] = __builtin_amdgcn_mfma_f32_16x16x32_bf16(
                    af[mt], bfr[nt], acc[mt][nt], 0, 0, 0);
    }
    // epilogue: C/D layout col=lane&15, row=(lane>>4)*4+reg  [m89-verified]
    int cc = lane & 15, cr = (lane >> 4) * 4;
#pragma unroll
    for (int mt = 0; mt < 4; ++mt)
#pragma unroll
        for (int nt = 0; nt < 5; ++nt)
#pragma unroll
            for (int r = 0; r < 4; ++r) {
                int row = m0 + wm + mt * 16 + cr + r;
                if (row < M)
                    C[(size_t)row * DP + n0 + wn + nt * 16 + cc] =
                        __float2bfloat16(acc[mt][nt][r]);
            }
}

// ---------------------------------------------------------------------------
// aggregation: h_pre[v][d<300] = sum_{in-edges} hw[src][d] + hw[v][d] + SV_l[v]
// edge loop 2x-unrolled with dual accumulator sets for memory-level parallelism.
// writes bf16 h_pre back into AH (gemm-input buffer, dead here); pads -> 0.
__global__ void agg_kernel(const __hip_bfloat16* __restrict__ HW,
                           const int* __restrict__ ptr, const int* __restrict__ src,
                           const float* __restrict__ SVl, __hip_bfloat16* __restrict__ AH) {
    int v = blockIdx.x * 4 + (threadIdx.x >> 6);
    int lane = threadIdx.x & 63;
    int beg = ptr[v], end = ptr[v + 1];
    // self term
    const __hip_bfloat162* ps = reinterpret_cast<const __hip_bfloat162*>(HW + (size_t)v * DP);
    __hip_bfloat162 sx0 = ps[lane], sx1 = ps[64 + lane];
    float a0 = __bfloat162float(sx0.x), a1 = __bfloat162float(sx0.y);
    float a2 = __bfloat162float(sx1.x), a3 = __bfloat162float(sx1.y);
    float a4 = __bfloat162float(HW[(size_t)v * DP + 256 + lane]);
    float b0 = 0.f, b1 = 0.f, b2 = 0.f, b3 = 0.f, b4 = 0.f;
    int i = beg;
    for (; i + 2 <= end; i += 2) {
        int s0 = src[i] & 0xFFFF, s1 = src[i + 1] & 0xFFFF;
        const __hip_bfloat162* p0 = reinterpret_cast<const __hip_bfloat162*>(HW + (size_t)s0 * DP);
        const __hip_bfloat162* p1 = reinterpret_cast<const __hip_bfloat162*>(HW + (size_t)s1 * DP);
        __hip_bfloat162 u0 = p0[lane], u1 = p0[64 + lane];
        float us = __bfloat162float(HW[(size_t)s0 * DP + 256 + lane]);
        __hip_bfloat162 w0 = p1[lane], w1 = p1[64 + lane];
        float ws = __bfloat162float(HW[(size_t)s1 * DP + 256 + lane]);
        a0 += __bfloat162float(u0.x); a1 += __bfloat162float(u0.y);
        a2 += __bfloat162float(u1.x); a3 += __bfloat162float(u1.y);
        a4 += us;
        b0 += __bfloat162float(w0.x); b1 += __bfloat162float(w0.y);
        b2 += __bfloat162float(w1.x); b3 += __bfloat162float(w1.y);
        b4 += ws;
    }
    if (i < end) {
        int s0 = src[i] & 0xFFFF;
        const __hip_bfloat162* p0 = reinterpret_cast<const __hip_bfloat162*>(HW + (size_t)s0 * DP);
        __hip_bfloat162 u0 = p0[lane], u1 = p0[64 + lane];
        float us = __bfloat162float(HW[(size_t)s0 * DP + 256 + lane]);
        a0 += __bfloat162float(u0.x); a1 += __bfloat162float(u0.y);
        a2 += __bfloat162float(u1.x); a3 += __bfloat162float(u1.y);
        a4 += us;
    }
    float sv = SVl[v];
    a0 += b0 + sv; a1 += b1 + sv; a2 += b2 + sv; a3 += b3 + sv; a4 += b4 + sv;
    __hip_bfloat16* out = AH + (size_t)v * DP;
    __hip_bfloat162 o0, o1;
    o0.x = __float2bfloat16(a0); o0.y = __float2bfloat16(a1);
    o1.x = __float2bfloat16(a2); o1.y = __float2bfloat16(a3);
    *reinterpret_cast<__hip_bfloat162*>(out + 2 * lane) = o0;
    *reinterpret_cast<__hip_bfloat162*>(out + 128 + 2 * lane) = o1;
    out[256 + lane] = __float2bfloat16(lane < 44 ? a4 : 0.f);  // 300..319 -> 0
}

// ---------------------------------------------------------------------------
// BN stats over bf16 h_pre (stride DP): sums[d], sums[DP+d]
__global__ void stats_kernel(const __hip_bfloat16* __restrict__ AH, float* __restrict__ sums) {
    int c = blockIdx.x;                 // dim chunk 0..4
    int tid = threadIdx.x;
    int dl = tid & 63, rl = tid >> 6;
    int d = c * 64 + dl;
    float s = 0.f, q = 0.f;
    if (d < DD) {
        for (int v = blockIdx.y * 4 + rl; v < NN; v += 256) {
            float x = __bfloat162float(AH[(size_t)v * DP + d]);
            s += x; q = fmaf(x, x, q);
        }
    }
    __shared__ float ls[256], lq[256];
    ls[tid] = s; lq[tid] = q;
    __syncthreads();
    if (tid < 64) {
        int dd = c * 64 + tid;
        if (dd < DD) {
            float ts = ls[tid] + ls[tid + 64] + ls[tid + 128] + ls[tid + 192];
            float tq = lq[tid] + lq[tid + 64] + lq[tid + 128] + lq[tid + 192];
            atomicAdd(&sums[dd], ts);
            atomicAdd(&sums[DP + dd], tq);
        }
    }
}

// writes scale/shift for ALL 320 dims: pad dims get 0/0 so the folded
// activation keeps GEMM A-padding at zero.
__global__ void finalize_kernel(const float* __restrict__ sums,
                                const float* __restrict__ gamma_l,
                                const float* __restrict__ beta_l,
                                float* __restrict__ scale, float* __restrict__ shift) {
    int d = threadIdx.x;                 // block of 320
    float sc = 0.f, sh = 0.f;
    if (d < DD) {
        const float invN = 1.0f / (float)NN;
        float mean = sums[d] * invN;
        float var = sums[DP + d] * invN - mean * mean;
        var = fmaxf(var, 0.f);                      // guard fp32 cancellation
        float rs = rsqrtf(var + 1e-5f);
        sc = rs * gamma_l[d];
        sh = beta_l[d] - mean * sc;
    }
    scale[d] = sc;
    shift[d] = sh;
}

// ---------------------------------------------------------------------------
__device__ __forceinline__ int lower_bound_dev(const int* b, int n, int key) {
    int lo = 0, hi = n;
    while (lo < hi) { int mid = (lo + hi) >> 1; if (b[mid] < key) lo = mid + 1; else hi = mid; }
    return lo;
}

// mean pool per graph over raw h_pre, then apply the (linear) BN affine of the
// last layer AFTER pooling: mean(s*x+t) = s*mean(x)+t. One wave per graph.
__global__ void pool_kernel(const __hip_bfloat16* __restrict__ A, const int* __restrict__ batch,
                            const float* __restrict__ scale, const float* __restrict__ shift,
                            float* __restrict__ HG) {
    int g = blockIdx.x * 4 + (threadIdx.x >> 6);
    int lane = threadIdx.x & 63;
    int lo = lower_bound_dev(batch, NN, g);
    int hi = lower_bound_dev(batch, NN, g + 1);
    float a0 = 0.f, a1 = 0.f, a2 = 0.f, a3 = 0.f, a4 = 0.f;
    for (int v = lo; v < hi; ++v) {
        const __hip_bfloat162* p = reinterpret_cast<const __hip_bfloat162*>(A + (size_t)v * DP);
        __hip_bfloat162 x0 = p[lane];
        __hip_bfloat162 x1 = p[64 + lane];
        float xs = __bfloat162float(A[(size_t)v * DP + 256 + lane]);
        a0 += __bfloat162float(x0.x); a1 += __bfloat162float(x0.y);
        a2 += __bfloat162float(x1.x); a3 += __bfloat162float(x1.y);
        a4 += xs;
    }
    int cnt = hi - lo;
    float inv = 1.0f / (float)(cnt > 0 ? cnt : 1);
    float2 sc0 = *reinterpret_cast<const float2*>(scale + 2 * lane);
    float2 sh0 = *reinterpret_cast<const float2*>(shift + 2 * lane);
    float2 sc1 = *reinterpret_cast<const float2*>(scale + 128 + 2 * lane);
    float2 sh1 = *reinterpret_cast<const float2*>(shift + 128 + 2 * lane);
    float scs = scale[256 + lane], shs = shift[256 + lane];
    float* out = HG + (size_t)g * DP;
    *reinterpret_cast<float2*>(out + 2 * lane) =
        make_float2(fmaf(a0 * inv, sc0.x, sh0.x), fmaf(a1 * inv, sc0.y, sh0.y));
    *reinterpret_cast<float2*>(out + 128 + 2 * lane) =
        make_float2(fmaf(a2 * inv, sc1.x, sh1.x), fmaf(a3 * inv, sc1.y, sh1.y));
    out[256 + lane] = fmaf(a4 * inv, scs, shs);   // pad dims: scale=shift=0 -> 0
}

// h_feat = hg @ feat_w + feat_b   (one block per graph), f32 out
__global__ void feat_kernel(const float* __restrict__ HG,
                            const float* __restrict__ fw,
                            const float* __restrict__ fb,
                            float* __restrict__ HFEAT, float* __restrict__ out0) {
    __shared__ float hgs[DD];
    int g = blockIdx.x, tid = threadIdx.x;
    for (int i = tid; i < DD; i += 256) hgs[i] = HG[(size_t)g * DP + i];
    __syncthreads();
    float acc = fb[tid];
#pragma unroll 4
    for (int k = 0; k < DD; ++k)
        acc = fmaf(hgs[k], fw[k * FEAT + tid], acc);
    HFEAT[g * FEAT + tid] = acc;
    out0[g * FEAT + tid] = acc;
}

// out = relu(h_feat @ w1 + b1) @ w2 + b2   (one block per graph), f32 out
__global__ void mlp_kernel(const float* __restrict__ HFEAT,
                           const float* __restrict__ w1, const float* __restrict__ b1,
                           const float* __restrict__ w2, const float* __restrict__ b2,
                           float* __restrict__ out1) {
    __shared__ float hf[FEAT], t[FEAT];
    int g = blockIdx.x, tid = threadIdx.x;
    hf[tid] = HFEAT[g * FEAT + tid];
    __syncthreads();
    float acc = b1[tid];
#pragma unroll 4
    for (int k = 0; k < FEAT; ++k)
        acc = fmaf(hf[k], w1[k * FEAT + tid], acc);
    t[tid] = fmaxf(acc, 0.f);
    __syncthreads();
    if (tid < FEAT / 2) {
        float acc2 = b2[tid];
#pragma unroll 4
        for (int k = 0; k < FEAT; ++k)
            acc2 = fmaf(t[k], w2[k * (FEAT / 2) + tid], acc2);
        out1[g * (FEAT / 2) + tid] = acc2;
    }
}

// ---------------------------------------------------------------------------
extern "C" void kernel_launch(void* const* d_in, const int* in_sizes, int n_in,
                              void* d_out, int out_size, void* d_ws, size_t ws_size,
                              hipStream_t stream) {
    const int* x     = (const int*)d_in[0];
    const int* ei    = (const int*)d_in[1];
    const int* ea    = (const int*)d_in[2];
    const int* batch = (const int*)d_in[3];
    const float* emb1  = (const float*)d_in[4];
    const float* emb2  = (const float*)d_in[5];
    const float* W     = (const float*)d_in[6];
    // d_in[7] = b[l]: per-dim constant, cancelled by BatchNorm -> unused
    const float* e1    = (const float*)d_in[8];
    const float* e2    = (const float*)d_in[9];
    const float* gamma = (const float*)d_in[10];
    const float* beta  = (const float*)d_in[11];
    const float* fw    = (const float*)d_in[12];
    const float* fb    = (const float*)d_in[13];
    const float* w1    = (const float*)d_in[14];
    const float* b1    = (const float*)d_in[15];
    const float* w2    = (const float*)d_in[16];
    const float* b2    = (const float*)d_in[17];

    // workspace carve (~71 MB total; small control buffers FIRST)
    char* base = (char*)d_ws;
    size_t off = 0;
    auto carve = [&](size_t bytes) -> void* {
        void* p = base + off;
        off = (off + bytes + 255) & ~(size_t)255;
        return p;
    };
    int*            PTR   = (int*)carve((size_t)(NN + 1) * 4);
    int*            CUR   = (int*)carve((size_t)NN * 4);
    int*            SRC   = (int*)carve((size_t)EE * 4);
    float*          SV    = (float*)carve((size_t)LL * NN * 4);
    int*            BSUM  = (int*)carve(256 * 4);
    float*          SUMS  = (float*)carve(2 * DP * 4);
    float*          SCALE = (float*)carve(DP * 4);
    float*          SHIFT = (float*)carve(DP * 4);
    float*          HG    = (float*)carve((size_t)GG * DP * 4);
    float*          HFEAT = (float*)carve((size_t)GG * FEAT * 4);
    __hip_bfloat16* WT    = (__hip_bfloat16*)carve((size_t)LL * DP * DP * 2);
    __hip_bfloat16* AH    = (__hip_bfloat16*)carve((size_t)NN * DP * 2);  // A / h_pre ping
    __hip_bfloat16* HWb   = (__hip_bfloat16*)carve((size_t)NN * DP * 2);  // gemm out pong

    float* out0 = (float*)d_out;                 // h_feat [G,256] f32
    float* out1 = (float*)d_out + GG * FEAT;     // out    [G,128] f32

    // ---- preprocess (ws is re-poisoned before every call) ----
    hipMemsetAsync(CUR, 0, (size_t)NN * 4, stream);
    embed_kernel<<<(NN * DP) / 256, 256, 0, stream>>>(x, emb1, emb2, AH);
    hist_kernel<<<EE / 256, 256, 0, stream>>>(ei, CUR);
    scan1_kernel<<<196, 256, 0, stream>>>(CUR, PTR, BSUM);
    scan2_kernel<<<1, 256, 0, stream>>>(BSUM);
    scan3_kernel<<<196, 256, 0, stream>>>(PTR, BSUM);
    hipMemsetAsync(CUR, 0, (size_t)NN * 4, stream);
    scatter_kernel<<<EE / 256, 256, 0, stream>>>(ei, ea, PTR, CUR, SRC);
    sv_kernel<<<196, 256, 0, stream>>>(PTR, SRC, e1, e2, SV);
    repack_kernel<<<(LL * DP * DP) / 256, 256, 0, stream>>>(W, WT);

    // ---- layers (BN+relu of layer l-1 folded into gemm A-staging of layer l) ----
    for (int l = 0; l < LL; ++l) {
        gemm_kernel<<<dim3(391, 2), 256, 0, stream>>>(AH, WT + (size_t)l * DP * DP, HWb, NN,
                                                      SCALE, SHIFT, l > 0 ? 1 : 0);
        agg_kernel<<<NN / 4, 256, 0, stream>>>(HWb, PTR, SRC, SV + (size_t)l * NN, AH);
        hipMemsetAsync(SUMS, 0, 2 * DP * 4, stream);
        stats_kernel<<<dim3(5, 64), 256, 0, stream>>>(AH, SUMS);
        finalize_kernel<<<1, 320, 0, stream>>>(SUMS, gamma + l * DD, beta + l * DD, SCALE, SHIFT);
    }

    // ---- head (BN affine of last layer applied after pooling — linear) ----
    pool_kernel<<<GG / 4, 256, 0, stream>>>(AH, batch, SCALE, SHIFT, HG);
    feat_kernel<<<GG, 256, 0, stream>>>(HG, fw, fb, HFEAT, out0);
    mlp_kernel<<<GG, 256, 0, stream>>>(HFEAT, w1, b1, w2, b2, out1);
}

// Round 6
// 1134.868 us; speedup vs baseline: 1.4185x; 1.0497x over previous
//
#include <hip/hip_runtime.h>
#include <hip/hip_bf16.h>

// Problem constants
#define NN 50000
#define EE 800000
#define GG 1024
#define DD 300
#define DP 320        // padded feature dim (multiple of 32 for MFMA K)
#define LL 5
#define FEAT 256

typedef __bf16 bf16x8 __attribute__((ext_vector_type(8)));
typedef float  f32x4  __attribute__((ext_vector_type(4)));

#define AS1 __attribute__((address_space(1)))
#define AS3 __attribute__((address_space(3)))

// async global->LDS, 16B per lane; LDS dst must be wave-uniform base + lane*16
__device__ __forceinline__ void dma16(const __hip_bfloat16* g, __hip_bfloat16* l) {
    auto gp = reinterpret_cast<const AS1 char*>(reinterpret_cast<uintptr_t>(g));
    auto lp = reinterpret_cast<AS3 char*>((unsigned int)(uintptr_t)l);
    __builtin_amdgcn_global_load_lds(gp, lp, 16, 0, 0);
}

// ---------------------------------------------------------------------------
// embed: AH[v][d] = x_emb1[x[v,0]][d] + x_emb2[x[v,1]][d]  (f32 in, bf16 out, pad 0)
__global__ void embed_kernel(const int* __restrict__ x,
                             const float* __restrict__ emb1,
                             const float* __restrict__ emb2,
                             __hip_bfloat16* __restrict__ A) {
    int idx = blockIdx.x * 256 + threadIdx.x;        // < NN*DP
    int v = idx / DP, d = idx % DP;
    float val = 0.f;
    if (d < DD) {
        int i0 = x[v * 2 + 0], i1 = x[v * 2 + 1];
        val = emb1[i0 * DD + d] + emb2[i1 * DD + d];
    }
    A[idx] = __float2bfloat16(val);
}

// ---------------------------------------------------------------------------
// histogram of destination (col) node degrees
__global__ void hist_kernel(const int* __restrict__ ei, int* __restrict__ deg) {
    int e = blockIdx.x * 256 + threadIdx.x;
    atomicAdd(&deg[ei[EE + e]], 1);
}

// 2-level exclusive scan
__global__ void scan1_kernel(const int* __restrict__ deg, int* __restrict__ ptr,
                             int* __restrict__ bsum) {
    __shared__ int buf[256];
    int tid = threadIdx.x;
    int i = blockIdx.x * 256 + tid;
    int v = (i < NN) ? deg[i] : 0;
    buf[tid] = v; __syncthreads();
    for (int off = 1; off < 256; off <<= 1) {
        int t = (tid >= off) ? buf[tid - off] : 0;
        __syncthreads();
        buf[tid] += t;
        __syncthreads();
    }
    if (i < NN) ptr[i + 1] = buf[tid];     // inclusive within block
    if (tid == 255) bsum[blockIdx.x] = buf[255];
}

__global__ void scan2_kernel(int* __restrict__ bsum) {   // 196 block sums -> exclusive
    __shared__ int buf[256];
    int tid = threadIdx.x;
    int v = (tid < 196) ? bsum[tid] : 0;
    buf[tid] = v; __syncthreads();
    for (int off = 1; off < 256; off <<= 1) {
        int t = (tid >= off) ? buf[tid - off] : 0;
        __syncthreads();
        buf[tid] += t;
        __syncthreads();
    }
    if (tid < 196) bsum[tid] = buf[tid] - v;  // exclusive
}

__global__ void scan3_kernel(int* __restrict__ ptr, const int* __restrict__ bsum) {
    int i = blockIdx.x * 256 + threadIdx.x;
    if (i < NN) ptr[i + 1] += bsum[blockIdx.x];
    if (i == 0) ptr[0] = 0;
}

// ---------------------------------------------------------------------------
// scatter edges into CSC src list; PACK edge attrs into spare bits of the src id
// (r < 65536 fits in 16 bits; a0,a1 in 2 bits each).
// (self_e and b[l] are per-dim constants -> cancelled exactly by BatchNorm; dropped.)
__global__ void scatter_kernel(const int* __restrict__ ei, const int* __restrict__ ea,
                               const int* __restrict__ ptr, int* __restrict__ cur,
                               int* __restrict__ srcout) {
    int e = blockIdx.x * 256 + threadIdx.x;
    int r = ei[e], c = ei[EE + e];
    int a0 = ea[e * 2 + 0], a1 = ea[e * 2 + 1];
    int pos = ptr[c] + atomicAdd(&cur[c], 1);
    srcout[pos] = r | (a0 << 16) | (a1 << 18);
}

// ---------------------------------------------------------------------------
// per-node per-layer edge-scalar sums, no atomics
__global__ void sv_kernel(const int* __restrict__ ptr, const int* __restrict__ src,
                          const float* __restrict__ e1, const float* __restrict__ e2,
                          float* __restrict__ SV) {
    int v = blockIdx.x * 256 + threadIdx.x;
    if (v >= NN) return;
    float c00 = 0.f, c01 = 0.f, c02 = 0.f, c10 = 0.f, c11 = 0.f, c12 = 0.f;
    int beg = ptr[v], end = ptr[v + 1];
    for (int i = beg; i < end; ++i) {
        int p = src[i];
        int e0 = (p >> 16) & 3, ev = (p >> 18) & 3;
        c00 += (e0 == 0); c01 += (e0 == 1); c02 += (e0 == 2);
        c10 += (ev == 0); c11 += (ev == 1); c12 += (ev == 2);
    }
#pragma unroll
    for (int l = 0; l < LL; ++l) {
        float s = c00 * e1[l * 5 + 0] + c01 * e1[l * 5 + 1] + c02 * e1[l * 5 + 2]
                + c10 * e2[l * 3 + 0] + c11 * e2[l * 3 + 1] + c12 * e2[l * 3 + 2];
        SV[l * NN + v] = s;
    }
}

// ---------------------------------------------------------------------------
// repack W[l] (k,n row-major, 300x300 f32) into TILED+SWIZZLED bf16 WT:
// layout = [l][ntile(2)][ktile(10)][tile: nn(160) x 4 units x 8 el], where the
// 16B unit at (nn, u) holds k = ktile*32 + u*8 .. +7 and sits at physical unit
// (u ^ (nn&3)) -> unpadded LDS image, ds_read_b128 2-way conflict (free, m136),
// and global_load_lds-streamable (contiguous, lane-ordered).
__global__ void repack_kernel(const float* __restrict__ W,
                              __hip_bfloat16* __restrict__ WT) {
    int idx = blockIdx.x * 256 + threadIdx.x;       // < LL*DP*DP
    int l = idx / (DP * DP);
    int r = idx - l * DP * DP;
    int ntile = r / 51200; r -= ntile * 51200;
    int ktile = r / 5120;  r -= ktile * 5120;
    int nn = r >> 5; r &= 31;
    int pu = r >> 3; int e = r & 7;
    int u = pu ^ (nn & 3);                 // logical k-unit stored at this slot
    int n = ntile * 160 + nn;
    int k = ktile * 32 + u * 8 + e;
    float v = 0.f;
    if (n < DD && k < DD) v = W[l * DD * DD + k * DD + n];
    WT[idx] = __float2bfloat16(v);
}

// ---------------------------------------------------------------------------
// GEMM: C[M x 320] = act(A) [M x 320] @ B [320 x 320].
// B comes pre-tiled/swizzled (repack_kernel); staged via global_load_lds (16B).
// fold!=0: act(x) = relu(x*scale[k]+shift[k]) applied during A-staging.
// 128x160 tile, BK=32, 4 waves, each wave 64x80 via 4x5 mfma_f32_16x16x32_bf16.
__global__ __launch_bounds__(256) void gemm_kernel(
        const __hip_bfloat16* __restrict__ A, const __hip_bfloat16* __restrict__ BT,
        __hip_bfloat16* __restrict__ C, int M,
        const float* __restrict__ scale, const float* __restrict__ shift, int fold) {
    __shared__ __align__(16) __hip_bfloat16 As[128 * 40];   // row stride 40 (pad 8)
    __shared__ __align__(16) __hip_bfloat16 Bs[160 * 32];   // swizzled, unpadded
    int tid = threadIdx.x;
    int m0 = blockIdx.x * 128;
    int wave = tid >> 6, lane = tid & 63;
    int wm = (wave >> 1) * 64, wn = (wave & 1) * 80;
    int fm = lane & 15, fu = lane >> 4;     // k-unit 0..3 (fk = fu*8)

    f32x4 acc[4][5];
#pragma unroll
    for (int i = 0; i < 4; ++i)
#pragma unroll
        for (int j = 0; j < 5; ++j) acc[i][j] = (f32x4){0.f, 0.f, 0.f, 0.f};

    const __hip_bfloat16* btile0 = BT + (size_t)blockIdx.y * 51200;

    for (int k0 = 0; k0 < DP; k0 += 32) {
        __syncthreads();
        // B tile: 640 x 16B units, async DMA straight to LDS (no VGPR roundtrip)
        const __hip_bfloat16* bt = btile0 + (k0 >> 5) * 5120;
        dma16(bt + (size_t)tid * 8, Bs + tid * 8);
        dma16(bt + (size_t)(tid + 256) * 8, Bs + (tid + 256) * 8);
        if (tid < 128) dma16(bt + (size_t)(tid + 512) * 8, Bs + (tid + 512) * 8);
        // A tile: VGPR path (BN+relu fold applied in-flight)
#pragma unroll
        for (int u = tid; u < 512; u += 256) {
            int r = u >> 2, p = u & 3;
            int gr = m0 + r;
            int4 val = make_int4(0, 0, 0, 0);
            if (gr < M) {
                val = *reinterpret_cast<const int4*>(A + (size_t)gr * DP + k0 + p * 8);
                if (fold) {
                    __hip_bfloat16* hh = reinterpret_cast<__hip_bfloat16*>(&val);
                    int kb = k0 + p * 8;
#pragma unroll
                    for (int j = 0; j < 8; ++j) {
                        float f = fmaf(__bfloat162float(hh[j]), scale[kb + j], shift[kb + j]);
                        hh[j] = __float2bfloat16(fmaxf(f, 0.f));
                    }
                }
            }
            *reinterpret_cast<int4*>(As + r * 40 + p * 8) = val;
        }
        __syncthreads();
        bf16x8 af[4], bfr[5];
#pragma unroll
        for (int mt = 0; mt < 4; ++mt)
            af[mt] = *reinterpret_cast<const bf16x8*>(As + (wm + mt * 16 + fm) * 40 + fu * 8);
#pragma unroll
        for (int nt = 0; nt < 5; ++nt) {
            int n = wn + nt * 16 + fm;
            bfr[nt] = *reinterpret_cast<const bf16x8*>(Bs + n * 32 + ((fu ^ (n & 3)) * 8));
        }
#pragma unroll
        for (int mt = 0; mt < 4; ++mt)
#pragma unroll
            for (int nt = 0; nt < 5; ++nt)
                acc[mt][nt] = __builtin_amdgcn_mfma_f32_16x16x32_bf16(
                    af[mt], bfr[nt], acc[mt][nt], 0, 0, 0);
    }
    // epilogue: C/D layout col=lane&15, row=(lane>>4)*4+reg  [m89-verified]
    int n0 = blockIdx.y * 160;
    int cc = lane & 15, cr = (lane >> 4) * 4;
#pragma unroll
    for (int mt = 0; mt < 4; ++mt)
#pragma unroll
        for (int nt = 0; nt < 5; ++nt)
#pragma unroll
            for (int r = 0; r < 4; ++r) {
                int row = m0 + wm + mt * 16 + cr + r;
                if (row < M)
                    C[(size_t)row * DP + n0 + wn + nt * 16 + cc] =
                        __float2bfloat16(acc[mt][nt][r]);
            }
}

// ---------------------------------------------------------------------------
// aggregation: h_pre[v][d<300] = sum_{in-edges} hw[src][d] + hw[v][d] + SV_l[v]
// lane covers dims {4L..4L+3} via one 8B load + dim 256+L via one 2B load.
// 4x-unrolled edge loop, 4 independent accumulator sets (~9 loads in flight).
__global__ void agg_kernel(const __hip_bfloat16* __restrict__ HW,
                           const int* __restrict__ ptr, const int* __restrict__ src,
                           const float* __restrict__ SVl, __hip_bfloat16* __restrict__ AH) {
    int v = blockIdx.x * 4 + (threadIdx.x >> 6);
    int lane = threadIdx.x & 63;
    int beg = ptr[v], end = ptr[v + 1];
    const __hip_bfloat16* rv = HW + (size_t)v * DP;
    // self term -> set 0
    ushort4 qs = *reinterpret_cast<const ushort4*>(rv + 4 * lane);
    unsigned int ts = reinterpret_cast<const unsigned short*>(rv)[256 + lane];
    float A0x = __uint_as_float((unsigned int)qs.x << 16);
    float A0y = __uint_as_float((unsigned int)qs.y << 16);
    float A0z = __uint_as_float((unsigned int)qs.z << 16);
    float A0w = __uint_as_float((unsigned int)qs.w << 16);
    float A0t = __uint_as_float(ts << 16);
    float A1x = 0.f, A1y = 0.f, A1z = 0.f, A1w = 0.f, A1t = 0.f;
    float A2x = 0.f, A2y = 0.f, A2z = 0.f, A2w = 0.f, A2t = 0.f;
    float A3x = 0.f, A3y = 0.f, A3z = 0.f, A3w = 0.f, A3t = 0.f;
    int i = beg;
    for (; i + 4 <= end; i += 4) {
        int s0 = src[i] & 0xFFFF, s1 = src[i + 1] & 0xFFFF;
        int s2 = src[i + 2] & 0xFFFF, s3 = src[i + 3] & 0xFFFF;
        const __hip_bfloat16* r0 = HW + (size_t)s0 * DP;
        const __hip_bfloat16* r1 = HW + (size_t)s1 * DP;
        const __hip_bfloat16* r2 = HW + (size_t)s2 * DP;
        const __hip_bfloat16* r3 = HW + (size_t)s3 * DP;
        ushort4 q0 = *reinterpret_cast<const ushort4*>(r0 + 4 * lane);
        ushort4 q1 = *reinterpret_cast<const ushort4*>(r1 + 4 * lane);
        ushort4 q2 = *reinterpret_cast<const ushort4*>(r2 + 4 * lane);
        ushort4 q3 = *reinterpret_cast<const ushort4*>(r3 + 4 * lane);
        unsigned int t0 = reinterpret_cast<const unsigned short*>(r0)[256 + lane];
        unsigned int t1 = reinterpret_cast<const unsigned short*>(r1)[256 + lane];
        unsigned int t2 = reinterpret_cast<const unsigned short*>(r2)[256 + lane];
        unsigned int t3 = reinterpret_cast<const unsigned short*>(r3)[256 + lane];
        A0x += __uint_as_float((unsigned int)q0.x << 16);
        A0y += __uint_as_float((unsigned int)q0.y << 16);
        A0z += __uint_as_float((unsigned int)q0.z << 16);
        A0w += __uint_as_float((unsigned int)q0.w << 16);
        A0t += __uint_as_float(t0 << 16);
        A1x += __uint_as_float((unsigned int)q1.x << 16);
        A1y += __uint_as_float((unsigned int)q1.y << 16);
        A1z += __uint_as_float((unsigned int)q1.z << 16);
        A1w += __uint_as_float((unsigned int)q1.w << 16);
        A1t += __uint_as_float(t1 << 16);
        A2x += __uint_as_float((unsigned int)q2.x << 16);
        A2y += __uint_as_float((unsigned int)q2.y << 16);
        A2z += __uint_as_float((unsigned int)q2.z << 16);
        A2w += __uint_as_float((unsigned int)q2.w << 16);
        A2t += __uint_as_float(t2 << 16);
        A3x += __uint_as_float((unsigned int)q3.x << 16);
        A3y += __uint_as_float((unsigned int)q3.y << 16);
        A3z += __uint_as_float((unsigned int)q3.z << 16);
        A3w += __uint_as_float((unsigned int)q3.w << 16);
        A3t += __uint_as_float(t3 << 16);
    }
    for (; i < end; ++i) {
        int s0 = src[i] & 0xFFFF;
        const __hip_bfloat16* r0 = HW + (size_t)s0 * DP;
        ushort4 q0 = *reinterpret_cast<const ushort4*>(r0 + 4 * lane);
        unsigned int t0 = reinterpret_cast<const unsigned short*>(r0)[256 + lane];
        A0x += __uint_as_float((unsigned int)q0.x << 16);
        A0y += __uint_as_float((unsigned int)q0.y << 16);
        A0z += __uint_as_float((unsigned int)q0.z << 16);
        A0w += __uint_as_float((unsigned int)q0.w << 16);
        A0t += __uint_as_float(t0 << 16);
    }
    float sv = SVl[v];
    float rx = A0x + A1x + A2x + A3x + sv;
    float ry = A0y + A1y + A2y + A3y + sv;
    float rz = A0z + A1z + A2z + A3z + sv;
    float rw = A0w + A1w + A2w + A3w + sv;
    float rt = A0t + A1t + A2t + A3t + sv;
    __hip_bfloat16* out = AH + (size_t)v * DP;
    union { ushort4 u; __hip_bfloat16 h[4]; } o;
    o.h[0] = __float2bfloat16(rx); o.h[1] = __float2bfloat16(ry);
    o.h[2] = __float2bfloat16(rz); o.h[3] = __float2bfloat16(rw);
    *reinterpret_cast<ushort4*>(out + 4 * lane) = o.u;
    out[256 + lane] = __float2bfloat16(lane < 44 ? rt : 0.f);  // 300..319 -> 0
}

// ---------------------------------------------------------------------------
// BN stats over bf16 h_pre (stride DP): sums[d], sums[DP+d]
__global__ void stats_kernel(const __hip_bfloat16* __restrict__ AH, float* __restrict__ sums) {
    int c = blockIdx.x;                 // dim chunk 0..4
    int tid = threadIdx.x;
    int dl = tid & 63, rl = tid >> 6;
    int d = c * 64 + dl;
    float s = 0.f, q = 0.f;
    if (d < DD) {
        for (int v = blockIdx.y * 4 + rl; v < NN; v += 256) {
            float x = __bfloat162float(AH[(size_t)v * DP + d]);
            s += x; q = fmaf(x, x, q);
        }
    }
    __shared__ float ls[256], lq[256];
    ls[tid] = s; lq[tid] = q;
    __syncthreads();
    if (tid < 64) {
        int dd = c * 64 + tid;
        if (dd < DD) {
            float ts = ls[tid] + ls[tid + 64] + ls[tid + 128] + ls[tid + 192];
            float tq = lq[tid] + lq[tid + 64] + lq[tid + 128] + lq[tid + 192];
            atomicAdd(&sums[dd], ts);
            atomicAdd(&sums[DP + dd], tq);
        }
    }
}

// writes scale/shift for ALL 320 dims: pad dims get 0/0 so the folded
// activation keeps GEMM A-padding at zero.
__global__ void finalize_kernel(const float* __restrict__ sums,
                                const float* __restrict__ gamma_l,
                                const float* __restrict__ beta_l,
                                float* __restrict__ scale, float* __restrict__ shift) {
    int d = threadIdx.x;                 // block of 320
    float sc = 0.f, sh = 0.f;
    if (d < DD) {
        const float invN = 1.0f / (float)NN;
        float mean = sums[d] * invN;
        float var = sums[DP + d] * invN - mean * mean;
        var = fmaxf(var, 0.f);                      // guard fp32 cancellation
        float rs = rsqrtf(var + 1e-5f);
        sc = rs * gamma_l[d];
        sh = beta_l[d] - mean * sc;
    }
    scale[d] = sc;
    shift[d] = sh;
}

// ---------------------------------------------------------------------------
__device__ __forceinline__ int lower_bound_dev(const int* b, int n, int key) {
    int lo = 0, hi = n;
    while (lo < hi) { int mid = (lo + hi) >> 1; if (b[mid] < key) lo = mid + 1; else hi = mid; }
    return lo;
}

// mean pool per graph over raw h_pre, then apply the (linear) BN affine of the
// last layer AFTER pooling: mean(s*x+t) = s*mean(x)+t. One wave per graph.
__global__ void pool_kernel(const __hip_bfloat16* __restrict__ A, const int* __restrict__ batch,
                            const float* __restrict__ scale, const float* __restrict__ shift,
                            float* __restrict__ HG) {
    int g = blockIdx.x * 4 + (threadIdx.x >> 6);
    int lane = threadIdx.x & 63;
    int lo = lower_bound_dev(batch, NN, g);
    int hi = lower_bound_dev(batch, NN, g + 1);
    float a0 = 0.f, a1 = 0.f, a2 = 0.f, a3 = 0.f, a4 = 0.f;
    for (int v = lo; v < hi; ++v) {
        const __hip_bfloat16* r = A + (size_t)v * DP;
        ushort4 q = *reinterpret_cast<const ushort4*>(r + 4 * lane);
        unsigned int t = reinterpret_cast<const unsigned short*>(r)[256 + lane];
        a0 += __uint_as_float((unsigned int)q.x << 16);
        a1 += __uint_as_float((unsigned int)q.y << 16);
        a2 += __uint_as_float((unsigned int)q.z << 16);
        a3 += __uint_as_float((unsigned int)q.w << 16);
        a4 += __uint_as_float(t << 16);
    }
    int cnt = hi - lo;
    float inv = 1.0f / (float)(cnt > 0 ? cnt : 1);
    float4 sc = *reinterpret_cast<const float4*>(scale + 4 * lane);
    float4 sh = *reinterpret_cast<const float4*>(shift + 4 * lane);
    float scs = scale[256 + lane], shs = shift[256 + lane];
    float* out = HG + (size_t)g * DP;
    *reinterpret_cast<float4*>(out + 4 * lane) =
        make_float4(fmaf(a0 * inv, sc.x, sh.x), fmaf(a1 * inv, sc.y, sh.y),
                    fmaf(a2 * inv, sc.z, sh.z), fmaf(a3 * inv, sc.w, sh.w));
    out[256 + lane] = fmaf(a4 * inv, scs, shs);   // pad dims: scale=shift=0 -> 0
}

// h_feat = hg @ feat_w + feat_b   (one block per graph), f32 out
__global__ void feat_kernel(const float* __restrict__ HG,
                            const float* __restrict__ fw,
                            const float* __restrict__ fb,
                            float* __restrict__ HFEAT, float* __restrict__ out0) {
    __shared__ float hgs[DD];
    int g = blockIdx.x, tid = threadIdx.x;
    for (int i = tid; i < DD; i += 256) hgs[i] = HG[(size_t)g * DP + i];
    __syncthreads();
    float acc = fb[tid];
#pragma unroll 4
    for (int k = 0; k < DD; ++k)
        acc = fmaf(hgs[k], fw[k * FEAT + tid], acc);
    HFEAT[g * FEAT + tid] = acc;
    out0[g * FEAT + tid] = acc;
}

// out = relu(h_feat @ w1 + b1) @ w2 + b2   (one block per graph), f32 out
__global__ void mlp_kernel(const float* __restrict__ HFEAT,
                           const float* __restrict__ w1, const float* __restrict__ b1,
                           const float* __restrict__ w2, const float* __restrict__ b2,
                           float* __restrict__ out1) {
    __shared__ float hf[FEAT], t[FEAT];
    int g = blockIdx.x, tid = threadIdx.x;
    hf[tid] = HFEAT[g * FEAT + tid];
    __syncthreads();
    float acc = b1[tid];
#pragma unroll 4
    for (int k = 0; k < FEAT; ++k)
        acc = fmaf(hf[k], w1[k * FEAT + tid], acc);
    t[tid] = fmaxf(acc, 0.f);
    __syncthreads();
    if (tid < FEAT / 2) {
        float acc2 = b2[tid];
#pragma unroll 4
        for (int k = 0; k < FEAT; ++k)
            acc2 = fmaf(t[k], w2[k * (FEAT / 2) + tid], acc2);
        out1[g * (FEAT / 2) + tid] = acc2;
    }
}

// ---------------------------------------------------------------------------
extern "C" void kernel_launch(void* const* d_in, const int* in_sizes, int n_in,
                              void* d_out, int out_size, void* d_ws, size_t ws_size,
                              hipStream_t stream) {
    const int* x     = (const int*)d_in[0];
    const int* ei    = (const int*)d_in[1];
    const int* ea    = (const int*)d_in[2];
    const int* batch = (const int*)d_in[3];
    const float* emb1  = (const float*)d_in[4];
    const float* emb2  = (const float*)d_in[5];
    const float* W     = (const float*)d_in[6];
    // d_in[7] = b[l]: per-dim constant, cancelled by BatchNorm -> unused
    const float* e1    = (const float*)d_in[8];
    const float* e2    = (const float*)d_in[9];
    const float* gamma = (const float*)d_in[10];
    const float* beta  = (const float*)d_in[11];
    const float* fw    = (const float*)d_in[12];
    const float* fb    = (const float*)d_in[13];
    const float* w1    = (const float*)d_in[14];
    const float* b1    = (const float*)d_in[15];
    const float* w2    = (const float*)d_in[16];
    const float* b2    = (const float*)d_in[17];

    // workspace carve (~71 MB total; small control buffers FIRST)
    char* base = (char*)d_ws;
    size_t off = 0;
    auto carve = [&](size_t bytes) -> void* {
        void* p = base + off;
        off = (off + bytes + 255) & ~(size_t)255;
        return p;
    };
    int*            PTR   = (int*)carve((size_t)(NN + 1) * 4);
    int*            CUR   = (int*)carve((size_t)NN * 4);
    int*            SRC   = (int*)carve((size_t)EE * 4);
    float*          SV    = (float*)carve((size_t)LL * NN * 4);
    int*            BSUM  = (int*)carve(256 * 4);
    float*          SUMS  = (float*)carve(2 * DP * 4);
    float*          SCALE = (float*)carve(DP * 4);
    float*          SHIFT = (float*)carve(DP * 4);
    float*          HG    = (float*)carve((size_t)GG * DP * 4);
    float*          HFEAT = (float*)carve((size_t)GG * FEAT * 4);
    __hip_bfloat16* WT    = (__hip_bfloat16*)carve((size_t)LL * DP * DP * 2);
    __hip_bfloat16* AH    = (__hip_bfloat16*)carve((size_t)NN * DP * 2);  // A / h_pre ping
    __hip_bfloat16* HWb   = (__hip_bfloat16*)carve((size_t)NN * DP * 2);  // gemm out pong

    float* out0 = (float*)d_out;                 // h_feat [G,256] f32
    float* out1 = (float*)d_out + GG * FEAT;     // out    [G,128] f32

    // ---- preprocess (ws is re-poisoned before every call) ----
    hipMemsetAsync(CUR, 0, (size_t)NN * 4, stream);
    embed_kernel<<<(NN * DP) / 256, 256, 0, stream>>>(x, emb1, emb2, AH);
    hist_kernel<<<EE / 256, 256, 0, stream>>>(ei, CUR);
    scan1_kernel<<<196, 256, 0, stream>>>(CUR, PTR, BSUM);
    scan2_kernel<<<1, 256, 0, stream>>>(BSUM);
    scan3_kernel<<<196, 256, 0, stream>>>(PTR, BSUM);
    hipMemsetAsync(CUR, 0, (size_t)NN * 4, stream);
    scatter_kernel<<<EE / 256, 256, 0, stream>>>(ei, ea, PTR, CUR, SRC);
    sv_kernel<<<196, 256, 0, stream>>>(PTR, SRC, e1, e2, SV);
    repack_kernel<<<(LL * DP * DP) / 256, 256, 0, stream>>>(W, WT);

    // ---- layers (BN+relu of layer l-1 folded into gemm A-staging of layer l) ----
    for (int l = 0; l < LL; ++l) {
        gemm_kernel<<<dim3(391, 2), 256, 0, stream>>>(AH, WT + (size_t)l * DP * DP, HWb, NN,
                                                      SCALE, SHIFT, l > 0 ? 1 : 0);
        agg_kernel<<<NN / 4, 256, 0, stream>>>(HWb, PTR, SRC, SV + (size_t)l * NN, AH);
        hipMemsetAsync(SUMS, 0, 2 * DP * 4, stream);
        stats_kernel<<<dim3(5, 64), 256, 0, stream>>>(AH, SUMS);
        finalize_kernel<<<1, 320, 0, stream>>>(SUMS, gamma + l * DD, beta + l * DD, SCALE, SHIFT);
    }

    // ---- head (BN affine of last layer applied after pooling — linear) ----
    pool_kernel<<<GG / 4, 256, 0, stream>>>(AH, batch, SCALE, SHIFT, HG);
    feat_kernel<<<GG, 256, 0, stream>>>(HG, fw, fb, HFEAT, out0);
    mlp_kernel<<<GG, 256, 0, stream>>>(HFEAT, w1, b1, w2, b2, out1);
}